// Round 2
// baseline (539.894 us; speedup 1.0000x reference)
//
#include <hip/hip_runtime.h>

// SoftMorphology: soft skeleton via iterative thinning.
//   erode(x)  = min over 5-point cross  (min(minpool3x1, minpool1x3))
//   dilate(x) = max over 3x3 window
//   open(x)   = dilate(erode(x))
//   skel = relu(img - open(img)); 10x: E=erode(E); delta=relu(E - open(E));
//          skel += relu(delta - skel*delta)
//
// Border semantics: +/-inf-padded pooling == index-clamped pooling for a
// SINGLE stage (clamped duplicate is an in-window in-bounds value; min/max
// idempotent). For the dilate-of-erode composition, the dilate must read the
// eroded field at IMAGE-clamped coordinates -- tile-halo eroded values at
// out-of-image positions are erode(extend(img)) != extend(erode(img)).
// (Round-1 bug: dilate read the bogus halo values -> skel underestimated.)
//
// Fused per-iteration kernel: tile of E_k (halo 2) -> LDS, erode -> LDS
// (halo 1), write E_{k+1}, dilate-of-erode with image-clamped indexing,
// update skel. 11 launches total.

#define W 1024
#define H 1024
#define NB 16
#define TX 64
#define TY 16

template <bool INIT>
__global__ __launch_bounds__(256) void fused_step(
    const float* __restrict__ in,   // E_k (or img for INIT)
    float* __restrict__ er_out,     // E_{k+1}
    float* __restrict__ skel) {
  __shared__ float s_in[TY + 4][TX + 4];   // input tile, halo 2
  __shared__ float s_er[TY + 2][TX + 2];   // eroded tile, halo 1

  const int x0 = blockIdx.x * TX;
  const int y0 = blockIdx.y * TY;
  const size_t base = (size_t)blockIdx.z * (size_t)(W * H);
  const int tid = threadIdx.y * TX + threadIdx.x;

  // Stage input tile with image-clamped borders (valid for single-stage min).
  for (int i = tid; i < (TY + 4) * (TX + 4); i += 256) {
    const int lx = i % (TX + 4);
    const int ly = i / (TX + 4);
    const int gx = min(max(x0 - 2 + lx, 0), W - 1);
    const int gy = min(max(y0 - 2 + ly, 0), H - 1);
    s_in[ly][lx] = in[base + (size_t)gy * W + gx];
  }
  __syncthreads();

  // Erode (5-point cross min) into halo-1 tile. s_er[ly][lx] corresponds to
  // image position (x0-1+lx, y0-1+ly); only in-image positions are valid.
  for (int i = tid; i < (TY + 2) * (TX + 2); i += 256) {
    const int lx = i % (TX + 2);
    const int ly = i / (TX + 2);
    const float c = s_in[ly + 1][lx + 1];
    const float v = fminf(fminf(s_in[ly][lx + 1], s_in[ly + 2][lx + 1]), c);
    const float h = fminf(s_in[ly + 1][lx], s_in[ly + 1][lx + 2]);
    s_er[ly][lx] = fminf(v, h);
  }
  __syncthreads();

  // Each thread: write eroded center, dilate(erode) with IMAGE-clamped
  // window indices, update skel.
#pragma unroll
  for (int j = 0; j < TY / 4; ++j) {
    const int lx = threadIdx.x;
    const int ly = threadIdx.y + 4 * j;
    const int gx = x0 + lx;
    const int gy = y0 + ly;
    const size_t idx = base + (size_t)gy * W + gx;

    // Tile-space indices of the image-clamped 3x3 dilate window.
    const int xm = max(gx - 1, 0) - x0 + 1;
    const int xc = lx + 1;
    const int xp = min(gx + 1, W - 1) - x0 + 1;
    const int ym = max(gy - 1, 0) - y0 + 1;
    const int yc = ly + 1;
    const int yp = min(gy + 1, H - 1) - y0 + 1;

    const float e = s_er[yc][xc];
    er_out[idx] = e;

    float d = fmaxf(s_er[ym][xm], s_er[ym][xc]);
    d = fmaxf(d, s_er[ym][xp]);
    d = fmaxf(d, s_er[yc][xm]);
    d = fmaxf(d, e);
    d = fmaxf(d, s_er[yc][xp]);
    d = fmaxf(d, s_er[yp][xm]);
    d = fmaxf(d, s_er[yp][xc]);
    d = fmaxf(d, s_er[yp][xp]);

    const float c = s_in[ly + 2][lx + 2];         // input at (gx, gy)
    const float delta = fmaxf(c - d, 0.0f);       // relu(E_k - open(E_k))
    if (INIT) {
      skel[idx] = delta;
    } else {
      float s = skel[idx];
      s = s + fmaxf(delta - s * delta, 0.0f);
      skel[idx] = s;
    }
  }
}

extern "C" void kernel_launch(void* const* d_in, const int* in_sizes, int n_in,
                              void* d_out, int out_size, void* d_ws,
                              size_t ws_size, hipStream_t stream) {
  const float* img = (const float*)d_in[0];
  float* skel = (float*)d_out;
  const size_t NPIX = (size_t)NB * W * H;

  float* A = (float*)d_ws;        // E_k
  float* B = A + NPIX;            // E_{k+1}  (needs 128 MiB total of d_ws)

  const int num_iter = 10;        // static per setup_inputs()

  dim3 grid(W / TX, H / TY, NB);
  dim3 block(TX, 4);

  // E1 = erode(img); skel = relu(img - dilate(E1))
  fused_step<true><<<grid, block, 0, stream>>>(img, A, skel);

  for (int k = 0; k < num_iter; ++k) {
    // B = erode(A); delta = relu(A - dilate(B)); skel += relu(delta - skel*delta)
    fused_step<false><<<grid, block, 0, stream>>>(A, B, skel);
    float* t = A;
    A = B;
    B = t;
  }
}

// Round 3
// 276.923 us; speedup vs baseline: 1.9496x; 1.9496x over previous
//
#include <hip/hip_runtime.h>

// SoftMorphology soft-skeleton, deep temporal fusion: 2 launches x 6 erosion
// stages. Launch 1: skel_init + iters 1..5, writes E_5 + skel. Launch 2:
// iters 6..10 from E_5, writes skel. Region per block: 80x48 f32 in LDS
// (tile 64x32 + halo 8 >= required 7 = 5 iters + dilate(erode) lookahead).
//
// Border semantics: out-of-image guard slots hold replicate-extended values
// (invariant). Staging clamps; after each erode, border blocks re-replicate
// one guard line per image edge. Region-edge clamped reads produce garbage
// that propagates <= 1 slot/stage inward; halo 8 > 7 keeps it dead.

#define W 1024
#define H 1024
#define TX 64
#define TY 32
#define HALO 8
#define RW (TX + 2 * HALO)  // 80
#define RH (TY + 2 * HALO)  // 48
#define NQ (RW / 4)         // 20 quads per region row
#define LSTR 84             // LDS row stride (floats), 16B-aligned, padded
#define NSTAGE 6

__device__ __forceinline__ float4 ldq(const float* b, int r, int c) {
  return *(const float4*)(b + r * LSTR + c);
}
__device__ __forceinline__ void stq(float* b, int r, int c, float4 v) {
  *(float4*)(b + r * LSTR + c) = v;
}
__device__ __forceinline__ float min5(float a, float b, float c, float d,
                                      float e) {
  return fminf(fminf(fminf(a, b), fminf(c, d)), e);
}
__device__ __forceinline__ float max3(float a, float b, float c) {
  return fmaxf(fmaxf(a, b), c);
}

template <bool FIRST>
__global__ __launch_bounds__(256, 4) void fused6(
    const float* __restrict__ in,   // img (FIRST) or E_5
    float* __restrict__ e_out,      // E_5 (FIRST only)
    float* __restrict__ skel) {
  __shared__ float buf0[RH * LSTR];
  __shared__ float buf1[RH * LSTR];

  const int tid = threadIdx.x;
  const int x0 = blockIdx.x * TX;
  const int y0 = blockIdx.y * TY;
  const size_t base = (size_t)blockIdx.z * (size_t)(W * H);

  const bool xlo = (x0 == 0), xhi = (x0 == W - TX);
  const bool ylo = (y0 == 0), yhi = (y0 == H - TY);
  const bool border = xlo || xhi || ylo || yhi;

  // ---- stage A_0 into buf0 ----
  if (!border) {
    const float* gp = in + base + (size_t)(y0 - HALO) * W + (x0 - HALO);
    for (int i = tid; i < RH * NQ; i += 256) {
      const int r = i / NQ;
      const int q = i - r * NQ;
      stq(buf0, r, 4 * q, *(const float4*)(gp + (size_t)r * W + 4 * q));
    }
  } else {
    for (int i = tid; i < RH * RW; i += 256) {
      const int r = i / RW;
      const int c = i - r * RW;
      const int gx = min(max(x0 - HALO + c, 0), W - 1);
      const int gy = min(max(y0 - HALO + r, 0), H - 1);
      buf0[r * LSTR + c] = in[base + (size_t)gy * W + gx];
    }
  }

  // ---- per-thread center mapping (update/store): 2 rows x 1 quad ----
  const int qc = tid & 15;        // quad col 0..15
  const int sr = tid >> 4;        // row pair 0..15
  const int cx = HALO + 4 * qc;   // slot x, 8..68
  const int cy = HALO + 2 * sr;   // slot rows cy, cy+1
  float* gsk = skel + base + (size_t)(y0 + 2 * sr) * W + (x0 + 4 * qc);
  float4 sk0, sk1;
  if (!FIRST) {
    sk0 = *(const float4*)gsk;
    sk1 = *(const float4*)(gsk + W);
  }

  // ---- erode mapping: 20 quad-cols x 12 strips of 4 rows ----
  const int eq = tid % 20;
  const int es = tid / 20;  // active if < 12
  const int ecol = 4 * eq;
  const int ecm = max(ecol - 4, 0);
  const int ecp = min(ecol + 4, RW - 4);

  float* pa = buf0;  // A_{t-1}
  float* pb = buf1;  // A_t

#pragma unroll 1
  for (int t = 1; t <= NSTAGE; ++t) {
    __syncthreads();

    if (es < 12) {
      const int r0 = 4 * es;
      float4 c0 = ldq(pa, max(r0 - 1, 0), ecol);
      float4 c1 = ldq(pa, r0 + 0, ecol);
      float4 c2 = ldq(pa, r0 + 1, ecol);
      float4 c3 = ldq(pa, r0 + 2, ecol);
      float4 c4 = ldq(pa, r0 + 3, ecol);
      float4 c5 = ldq(pa, min(r0 + 4, RH - 1), ecol);
      float4 p0 = ldq(pa, r0 + 0, ecm), p1 = ldq(pa, r0 + 1, ecm);
      float4 p2 = ldq(pa, r0 + 2, ecm), p3 = ldq(pa, r0 + 3, ecm);
      float4 n0 = ldq(pa, r0 + 0, ecp), n1 = ldq(pa, r0 + 1, ecp);
      float4 n2 = ldq(pa, r0 + 2, ecp), n3 = ldq(pa, r0 + 3, ecp);
      float4 e;
#define ERODE_ROW(up, cn, dn, pv, nx, row)                \
  e.x = min5(cn.x, up.x, dn.x, pv.w, cn.y);               \
  e.y = min5(cn.y, up.y, dn.y, cn.x, cn.z);               \
  e.z = min5(cn.z, up.z, dn.z, cn.y, cn.w);               \
  e.w = min5(cn.w, up.w, dn.w, cn.z, nx.x);               \
  stq(pb, row, ecol, e)
      ERODE_ROW(c0, c1, c2, p0, n0, r0 + 0);
      ERODE_ROW(c1, c2, c3, p1, n1, r0 + 1);
      ERODE_ROW(c2, c3, c4, p2, n2, r0 + 2);
      ERODE_ROW(c3, c4, c5, p3, n3, r0 + 3);
#undef ERODE_ROW
    }
    __syncthreads();

    if (border) {
      // re-establish extend-invariant on one guard line per image edge
      const int losx = xlo ? HALO : 0;
      const int hisx = xhi ? (TX - 1 + HALO) : (RW - 1);  // 71 or 79
      const int losy = ylo ? HALO : 0;
      const int hisy = yhi ? (TY - 1 + HALO) : (RH - 1);  // 39 or 47
      if (tid < RH) {
        const int ry = min(max(tid, losy), hisy);
        if (xlo) pb[tid * LSTR + (HALO - 1)] = pb[ry * LSTR + HALO];
        if (xhi) pb[tid * LSTR + (hisx + 1)] = pb[ry * LSTR + hisx];
      }
      if (tid < RW) {
        const int rx = min(max(tid, losx), hisx);
        if (ylo) pb[(HALO - 1) * LSTR + tid] = pb[HALO * LSTR + rx];
        if (yhi) pb[(hisy + 1) * LSTR + tid] = pb[hisy * LSTR + rx];
      }
      __syncthreads();
    }

    // ---- update: delta = relu(A_{t-1} - dilate3x3(A_t)); skel update ----
    if (FIRST || t >= 2) {
      float4 am0 = ldq(pb, cy - 1, cx - 4), a0 = ldq(pb, cy - 1, cx),
             ap0 = ldq(pb, cy - 1, cx + 4);
      float4 am1 = ldq(pb, cy + 0, cx - 4), a1 = ldq(pb, cy + 0, cx),
             ap1 = ldq(pb, cy + 0, cx + 4);
      float4 am2 = ldq(pb, cy + 1, cx - 4), a2 = ldq(pb, cy + 1, cx),
             ap2 = ldq(pb, cy + 1, cx + 4);
      float4 am3 = ldq(pb, cy + 2, cx - 4), a3 = ldq(pb, cy + 2, cx),
             ap3 = ldq(pb, cy + 2, cx + 4);
      float4 h0, h1, h2, h3;
#define HMAX(h, am, a, ap)              \
  h.x = max3(am.w, a.x, a.y);           \
  h.y = max3(a.x, a.y, a.z);            \
  h.z = max3(a.y, a.z, a.w);            \
  h.w = max3(a.z, a.w, ap.x)
      HMAX(h0, am0, a0, ap0);
      HMAX(h1, am1, a1, ap1);
      HMAX(h2, am2, a2, ap2);
      HMAX(h3, am3, a3, ap3);
#undef HMAX
      float4 d0, d1;
      d0.x = max3(h0.x, h1.x, h2.x);
      d0.y = max3(h0.y, h1.y, h2.y);
      d0.z = max3(h0.z, h1.z, h2.z);
      d0.w = max3(h0.w, h1.w, h2.w);
      d1.x = max3(h1.x, h2.x, h3.x);
      d1.y = max3(h1.y, h2.y, h3.y);
      d1.z = max3(h1.z, h2.z, h3.z);
      d1.w = max3(h1.w, h2.w, h3.w);
      const float4 g0 = ldq(pa, cy, cx);
      const float4 g1 = ldq(pa, cy + 1, cx);
      float4 dl0, dl1;
      dl0.x = fmaxf(g0.x - d0.x, 0.f);
      dl0.y = fmaxf(g0.y - d0.y, 0.f);
      dl0.z = fmaxf(g0.z - d0.z, 0.f);
      dl0.w = fmaxf(g0.w - d0.w, 0.f);
      dl1.x = fmaxf(g1.x - d1.x, 0.f);
      dl1.y = fmaxf(g1.y - d1.y, 0.f);
      dl1.z = fmaxf(g1.z - d1.z, 0.f);
      dl1.w = fmaxf(g1.w - d1.w, 0.f);
      if (FIRST && t == 1) {
        sk0 = dl0;
        sk1 = dl1;
      } else {
#define SKUP(s, d) s = s + fmaxf(d - s * d, 0.f)
        SKUP(sk0.x, dl0.x); SKUP(sk0.y, dl0.y);
        SKUP(sk0.z, dl0.z); SKUP(sk0.w, dl0.w);
        SKUP(sk1.x, dl1.x); SKUP(sk1.y, dl1.y);
        SKUP(sk1.z, dl1.z); SKUP(sk1.w, dl1.w);
#undef SKUP
      }
    }

    // swap ping/pong
    float* tmp = pa;
    pa = pb;
    pb = tmp;
  }

  // ---- final stores (A_5 lives in buf1; last LDS writes were stage 6) ----
  *(float4*)gsk = sk0;
  *(float4*)(gsk + W) = sk1;
  if (FIRST) {
    const float4 e0 = ldq(buf1, cy, cx);
    const float4 e1 = ldq(buf1, cy + 1, cx);
    float* ge = e_out + base + (size_t)(y0 + 2 * sr) * W + (x0 + 4 * qc);
    *(float4*)ge = e0;
    *(float4*)(ge + W) = e1;
  }
}

extern "C" void kernel_launch(void* const* d_in, const int* in_sizes, int n_in,
                              void* d_out, int out_size, void* d_ws,
                              size_t ws_size, hipStream_t stream) {
  const float* img = (const float*)d_in[0];
  float* skel = (float*)d_out;
  float* E = (float*)d_ws;  // 64 MiB: E_5 between the two launches

  dim3 grid(W / TX, H / TY, 16);
  // Launch 1: skel = init + iters 1..5; writes E_5.
  fused6<true><<<grid, 256, 0, stream>>>(img, E, skel);
  // Launch 2: iters 6..10 from E_5; skel final.
  fused6<false><<<grid, 256, 0, stream>>>(E, E, skel);
}